// Round 1
// baseline (314.510 us; speedup 1.0000x reference)
//
#include <hip/hip_runtime.h>

// SpatialDisplConv (separable 12x12 displaced gather-conv)
// B=4 C=3 H=W=512 K=11, input1 padded to 522x522.

constexpr int B  = 4;
constexpr int C  = 3;
constexpr int H  = 512;
constexpr int W  = 512;
constexpr int K  = 11;
constexpr int KP = K + 1;              // 12
constexpr int Hp = H + K - 1;          // 522
constexpr int Wp = W + K - 1;          // 522
constexpr int HW = H * W;
constexpr int PLANE1 = Hp * Wp;        // input1 plane per channel

__global__ __launch_bounds__(256) void sdc_kernel(
    const float* __restrict__ in1,   // [B][C][Hp][Wp]
    const float* __restrict__ in2,   // [B][K][H][W]
    const float* __restrict__ in3,   // [B][K][H][W]
    const float* __restrict__ in4,   // [B][2][H][W]
    float* __restrict__ out)         // [B][C][H][W]
{
    int idx = blockIdx.x * blockDim.x + threadIdx.x;
    if (idx >= B * HW) return;
    int w = idx & (W - 1);
    int h = (idx >> 9) & (H - 1);
    int b = idx >> 18;

    const int pix = h * W + w;
    const float dx = in4[(b * 2 + 0) * HW + pix];
    const float dy = in4[(b * 2 + 1) * HW + pix];

    const float py  = (float)h + dy;
    const float px  = (float)w + dx;
    const float fy0 = floorf(py);
    const float fx0 = floorf(px);
    const float wy  = py - fy0;
    const float wx  = px - fx0;
    const int   iy0 = (int)fy0;
    const int   ix0 = (int)fx0;

    // Vy[g] = in2[g]*(1-wy) + in2[g-1]*wy   (g in [0,12), in2[-1]=in2[11]=0)
    float Vy[KP], Hx[KP];
    {
        const float* p2 = in2 + b * K * HW + pix;
        const float* p3 = in3 + b * K * HW + pix;
        float v2[K], v3[K];
        #pragma unroll
        for (int k = 0; k < K; ++k) {
            v2[k] = p2[k * HW];
            v3[k] = p3[k * HW];
        }
        const float omwy = 1.f - wy;
        const float omwx = 1.f - wx;
        #pragma unroll
        for (int g = 0; g < KP; ++g) {
            float a2 = (g < K) ? v2[g] : 0.f;
            float b2 = (g > 0) ? v2[g - 1] : 0.f;
            Vy[g] = a2 * omwy + b2 * wy;
            float a3 = (g < K) ? v3[g] : 0.f;
            float b3 = (g > 0) ? v3[g - 1] : 0.f;
            Hx[g] = a3 * omwx + b3 * wx;
        }
    }

    // Fold column validity into Hx (clamp index, zero weight) — matches
    // reference clip+mask semantics.
    float Hxe[KP];
    int   ixc[KP];
    #pragma unroll
    for (int gx = 0; gx < KP; ++gx) {
        int ix = ix0 + gx;
        bool valid = (ix >= 0) && (ix < Wp);
        Hxe[gx] = valid ? Hx[gx] : 0.f;
        ixc[gx] = valid ? ix : 0;
    }

    float acc0 = 0.f, acc1 = 0.f, acc2 = 0.f;
    const float* base1 = in1 + b * C * PLANE1;

    #pragma unroll 1
    for (int gy = 0; gy < KP; ++gy) {
        int iy = iy0 + gy;
        if (iy < 0 || iy >= Hp) continue;
        const float vy = Vy[gy];
        const float* r = base1 + iy * Wp;
        float s0 = 0.f, s1 = 0.f, s2 = 0.f;
        #pragma unroll
        for (int gx = 0; gx < KP; ++gx) {
            const float hx = Hxe[gx];
            const int   ix = ixc[gx];
            s0 += hx * r[ix];
            s1 += hx * r[PLANE1 + ix];
            s2 += hx * r[2 * PLANE1 + ix];
        }
        acc0 += vy * s0;
        acc1 += vy * s1;
        acc2 += vy * s2;
    }

    float* po = out + b * C * HW + pix;
    po[0]      = acc0;
    po[HW]     = acc1;
    po[2 * HW] = acc2;
}

extern "C" void kernel_launch(void* const* d_in, const int* in_sizes, int n_in,
                              void* d_out, int out_size, void* d_ws, size_t ws_size,
                              hipStream_t stream) {
    const float* in1 = (const float*)d_in[0];
    const float* in2 = (const float*)d_in[1];
    const float* in3 = (const float*)d_in[2];
    const float* in4 = (const float*)d_in[3];
    float* out = (float*)d_out;

    const int total = B * HW;           // 1,048,576 threads
    const int block = 256;
    const int grid = (total + block - 1) / block;
    sdc_kernel<<<grid, block, 0, stream>>>(in1, in2, in3, in4, out);
}